// Round 15
// baseline (1411.229 us; speedup 1.0000x reference)
//
#include <hip/hip_runtime.h>
#include <stdint.h>

#define NEGV (-1000000000.0f)

typedef float  f32x4  __attribute__((ext_vector_type(4)));
typedef __bf16 bf16x8 __attribute__((ext_vector_type(8)));

#define KEEP1(x) asm volatile("" :: "v"(x))
#define KEEP4(v) asm volatile("" :: "v"((v).x), "v"((v).y), "v"((v).z), "v"((v).w))

__device__ __forceinline__ unsigned short f2bf(float f){
  union { float f; unsigned u; } v; v.f = f;
  unsigned r = v.u + 0x7FFFu + ((v.u >> 16) & 1u);
  return (unsigned short)(r >> 16);
}
__device__ __forceinline__ unsigned packbf2(float a, float b){
  return (unsigned)f2bf(a) | ((unsigned)f2bf(b) << 16);
}
__device__ __forceinline__ void gl_lds16(const void* g, const char* l){
  __builtin_amdgcn_global_load_lds(
      (const __attribute__((address_space(1))) void*)g,
      (__attribute__((address_space(3))) void*)(unsigned)(uintptr_t)l,
      16, 0, 0);
}

// ws layouts (per batch, 128 KB each) — FRAGMENT-CONTIGUOUS:
//  qbf : frag[ch][ks][j][64B]   ch=k/64, ks=(k/32)&1, j=0..127
//  qtbf: frag[hch][ks][hr][64B] hch=h/64, ks=j/32,    hr=h&63

// ---------------- K0: Q -> packed bf16 fragments, s_q partials -------------
__global__ __launch_bounds__(256) void k0_prep(const float* __restrict__ Q,
                                               const float* __restrict__ w,
                                               char* __restrict__ qbf,
                                               char* __restrict__ qtbf,
                                               float* __restrict__ sq_part)
{
  __shared__ float tile[128][129];
  __shared__ float sqs[128];
  const int bid = blockIdx.x, t = threadIdx.x;
  const int b = bid >> 2, hc = bid & 3;
  if (t < 128) sqs[t] = 0.f;
  __syncthreads();
  for (int it = 0; it < 16; ++it){
    int idx = it*256 + t;
    int j = idx >> 5, h4 = idx & 31;
    const f32x4 q4 = *(const f32x4*)(Q + ((size_t)b*128 + j)*512 + hc*128 + h4*4);
    *(f32x4*)(&tile[j][h4*4]) = q4;
    unsigned lo = packbf2(q4.x, q4.y), hi = packbf2(q4.z, q4.w);
    int k = hc*128 + h4*4;
    int o = (k >> 6)*16384 + (((k >> 5) & 1))*8192 + j*64 + (k & 31)*2;
    char* dst = qbf + (size_t)b*131072 + o;
    *(unsigned*)dst = lo; *(unsigned*)(dst + 4) = hi;
    const float* w2 = w + 512 + k;
    float p = q4.x*w2[0] + q4.y*w2[1] + q4.z*w2[2] + q4.w*w2[3];
    for (int s = 16; s > 0; s >>= 1) p += __shfl_down(p, s, 32);
    if ((t & 31) == 0) sqs[j] += p;
  }
  __syncthreads();
  for (int it = 0; it < 32; ++it){
    int idx = it*256 + t;
    int hr = idx >> 6, j2 = idx & 63;
    float a = tile[j2*2][hr], c = tile[j2*2+1][hr];
    int h = hc*128 + hr;
    int o = (h >> 6)*16384 + (j2 >> 4)*4096 + (h & 63)*64 + (j2 & 15)*4;
    *(unsigned*)(qtbf + (size_t)b*131072 + o) = packbf2(a, c);
  }
  if (t < 128) sq_part[(size_t)(b*4 + hc)*128 + t] = sqs[t];
}

// ---- MEASUREMENT: full K1 body minus ALL global stores, x12 reps ----------
__global__ __launch_bounds__(512, 6) void k1v_nostores(
    const float* __restrict__ C, const int* __restrict__ qmask,
    const float* __restrict__ w, const float* __restrict__ sq_part,
    const char* __restrict__ qbf, const char* __restrict__ qtbf,
    float* __restrict__ dump)
{
  __shared__ __align__(16) char lds_c[32768];
  __shared__ __align__(16) char cw[4096];
  __shared__ float w1l[512], w3l[512];
  __shared__ float sqf[128];
  __shared__ int   msk[128];
  __shared__ float exf[16];
  __shared__ float mh[8][16], sh[8][16];

  const int t = threadIdx.x, bid = blockIdx.x;
  const int xcd = bid & 7, jj = bid >> 3;
  const int b = xcd*4 + (jj >> 6), i0 = (jj & 63)*16;
  const int wv = t >> 6, ln = t & 63;
  const int g = ln >> 4, c16 = ln & 15;
  const int iloc = c16;
  const int swz = ((iloc & 7) << 4) | (((iloc >> 3) & 1) << 7);

  if (t < 128){
    sqf[t] = sq_part[(size_t)(b*4 + 0)*128 + t] + sq_part[(size_t)(b*4 + 1)*128 + t]
           + sq_part[(size_t)(b*4 + 2)*128 + t] + sq_part[(size_t)(b*4 + 3)*128 + t];
    msk[t] = qmask[b*128 + t];
  }
  w1l[t] = w[t];
  w3l[t] = w[1024 + t];
  const char* qsrc  = qbf  + (size_t)b * 131072;
  const char* qtsrc = qtbf + (size_t)b * 131072;
  float keep = 0.f;

  for (int rep = 0; rep < 12; ++rep){
    __syncthreads();   // prior rep's lds_c reads complete before re-stage
    {
      const char* ctile = (const char*)(C + (size_t)(b*1024 + i0)*512);
      #pragma unroll
      for (int r = 0; r < 4; ++r){
        const int ob  = wv*4096 + r*1024;
        const int row = ob >> 11;
        const int msw = ((row & 7) << 4) | (((row >> 3) & 1) << 7);
        gl_lds16(ctile + ob + ((ln << 4) ^ msw), lds_c + ob);
      }
    }
    __syncthreads();

    // S-phase (R10 form)
    float scp = 0.f;
    f32x4 acc = {};
    #pragma unroll
    for (int ch = 0; ch < 8; ++ch){
      #pragma unroll
      for (int ks = 0; ks < 2; ++ks){
        const int k0 = ch*64 + ks*32 + g*8;
        const int lo = iloc*2048 + k0*4;
        const f32x4 cA  = *(const f32x4*)(lds_c + (lo ^ swz));
        const f32x4 cB  = *(const f32x4*)(lds_c + ((lo + 16) ^ swz));
        const f32x4 w3A = *(const f32x4*)(w3l + k0);
        const f32x4 w3B = *(const f32x4*)(w3l + k0 + 4);
        const f32x4 w1A = *(const f32x4*)(w1l + k0);
        const f32x4 w1B = *(const f32x4*)(w1l + k0 + 4);
        scp += cA.x*w1A.x + cA.y*w1A.y + cA.z*w1A.z + cA.w*w1A.w
             + cB.x*w1B.x + cB.y*w1B.y + cB.z*w1B.z + cB.w*w1B.w;
        bf16x8 bv;
        bv[0] = (__bf16)(cA.x*w3A.x); bv[1] = (__bf16)(cA.y*w3A.y);
        bv[2] = (__bf16)(cA.z*w3A.z); bv[3] = (__bf16)(cA.w*w3A.w);
        bv[4] = (__bf16)(cB.x*w3B.x); bv[5] = (__bf16)(cB.y*w3B.y);
        bv[6] = (__bf16)(cB.z*w3B.z); bv[7] = (__bf16)(cB.w*w3B.w);
        const int j = wv*16 + c16;
        bf16x8 av = *(const bf16x8*)(qsrc + ch*16384 + ks*8192 + j*64 + g*16);
        acc = __builtin_amdgcn_mfma_f32_16x16x32_bf16(av, bv, acc, 0, 0, 0);
      }
    }
    scp += __shfl_xor(scp, 16);
    scp += __shfl_xor(scp, 32);
    const float sc = scp;

    float m = -3.0e38f;
    #pragma unroll
    for (int r = 0; r < 4; ++r){
      int jj2 = wv*16 + g*4 + r;
      float v = msk[jj2] ? (acc[r] + sc + sqf[jj2]) : NEGV;
      acc[r] = v;
      m = fmaxf(m, v);
    }
    m = fmaxf(m, __shfl_xor(m, 16));
    m = fmaxf(m, __shfl_xor(m, 32));
    float s = 0.f;
    #pragma unroll
    for (int r = 0; r < 4; ++r){
      float e = __expf(acc[r] - m);
      acc[r] = e; s += e;
    }
    s += __shfl_xor(s, 16);
    s += __shfl_xor(s, 32);
    if (g == 0){ mh[wv][iloc] = m; sh[wv][iloc] = s; }
    __syncthreads();

    float mF = mh[0][iloc];
    #pragma unroll
    for (int q = 1; q < 8; ++q) mF = fmaxf(mF, mh[q][iloc]);
    float sF = 0.f;
    #pragma unroll
    for (int q = 0; q < 8; ++q) sF += sh[q][iloc]*__expf(mh[q][iloc] - mF);
    const float scale = __expf(m - mF) / sF;
    {
      uint64_t pk = (uint64_t)packbf2(acc[0]*scale, acc[1]*scale)
                  | ((uint64_t)packbf2(acc[2]*scale, acc[3]*scale) << 32);
      *(uint64_t*)(cw + ((iloc*256 + wv*32 + g*8) ^ ((iloc & 7) << 4))) = pk;
    }
    if (wv == 0 && g == 0) exf[iloc] = __expf(mF);
    __syncthreads();

    // PV (R10 form) — stores replaced by keeps
    bf16x8 pb[4];
    #pragma unroll
    for (int ks = 0; ks < 4; ++ks)
      pb[ks] = *(const bf16x8*)(cw + ((iloc*256 + ks*64 + g*16) ^ ((iloc & 7) << 4)));

    f32x4 a2[4] = {};
    #pragma unroll
    for (int nf = 0; nf < 4; ++nf){
      int hr = nf*16 + c16;
      #pragma unroll
      for (int ks = 0; ks < 4; ++ks){
        bf16x8 qa = *(const bf16x8*)(qtsrc + wv*16384 + ks*4096 + hr*64 + g*16);
        a2[nf] = __builtin_amdgcn_mfma_f32_16x16x32_bf16(qa, pb[ks], a2[nf], 0, 0, 0);
      }
    }
    #pragma unroll
    for (int nf = 0; nf < 4; ++nf){
      int h = wv*64 + nf*16 + g*4;
      const int lo = iloc*2048 + h*4;
      const f32x4 c4 = *(const f32x4*)(lds_c + (lo ^ swz));
      f32x4 av = a2[nf];
      f32x4 ca = av * c4;
      KEEP4(av); KEEP4(ca); KEEP4(c4);   // rule #17: keep live, no stores
    }

    float n0 = 0.f;
    #pragma unroll
    for (int i2 = 0; i2 < 16; ++i2){
      const int ms = ((i2 & 7) << 4) | (((i2 >> 3) & 1) << 7);
      n0 += exf[i2] * *(const float*)(lds_c + ((i2*2048 + t*4) ^ ms));
    }
    KEEP1(n0);
    keep += n0;
  }
  dump[(size_t)bid*512 + t] = keep;
}

// -------- K1: R10-best (16-row tiles, 3 blocks/CU, contiguous Q frags) -----
__global__ __launch_bounds__(512, 6) void k1_main(
    const float* __restrict__ C, const int* __restrict__ qmask,
    const float* __restrict__ w, const float* __restrict__ sq_part,
    const char* __restrict__ qbf, const char* __restrict__ qtbf,
    float* __restrict__ out, float* __restrict__ num_part,
    float* __restrict__ den_part)
{
  __shared__ __align__(16) char lds_c[32768];
  __shared__ __align__(16) char cw[4096];
  __shared__ float w1l[512], w3l[512];
  __shared__ float sqf[128];
  __shared__ int   msk[128];
  __shared__ float exf[16];
  __shared__ float mh[8][16], sh[8][16];

  const int t = threadIdx.x;
  const int bid = blockIdx.x;
  const int xcd = bid & 7, jj = bid >> 3;
  const int b = xcd*4 + (jj >> 6), itile = jj & 63;
  const int i0 = itile * 16;
  const int wv = t >> 6, ln = t & 63;
  const int g = ln >> 4, c16 = ln & 15;
  const int iloc = c16;

  {
    const char* ctile = (const char*)(C + (size_t)(b*1024 + i0)*512);
    #pragma unroll
    for (int r = 0; r < 4; ++r){
      const int ob  = wv*4096 + r*1024;
      const int row = ob >> 11;
      const int msw = ((row & 7) << 4) | (((row >> 3) & 1) << 7);
      gl_lds16(ctile + ob + ((ln << 4) ^ msw), lds_c + ob);
    }
  }
  if (t < 128){
    sqf[t] = sq_part[(size_t)(b*4 + 0)*128 + t] + sq_part[(size_t)(b*4 + 1)*128 + t]
           + sq_part[(size_t)(b*4 + 2)*128 + t] + sq_part[(size_t)(b*4 + 3)*128 + t];
    msk[t] = qmask[b*128 + t];
  }
  w1l[t] = w[t];
  w3l[t] = w[1024 + t];
  __syncthreads();

  const char* qsrc  = qbf  + (size_t)b * 131072;
  const char* qtsrc = qtbf + (size_t)b * 131072;
  const size_t rowb = (size_t)(b*1024 + i0 + iloc);
  const int swz = ((iloc & 7) << 4) | (((iloc >> 3) & 1) << 7);

  float scp = 0.f;
  f32x4 acc = {};
  #pragma unroll
  for (int ch = 0; ch < 8; ++ch){
    #pragma unroll
    for (int ks = 0; ks < 2; ++ks){
      const int k0 = ch*64 + ks*32 + g*8;
      const int lo = iloc*2048 + k0*4;
      const f32x4 cA  = *(const f32x4*)(lds_c + (lo ^ swz));
      const f32x4 cB  = *(const f32x4*)(lds_c + ((lo + 16) ^ swz));
      const f32x4 w3A = *(const f32x4*)(w3l + k0);
      const f32x4 w3B = *(const f32x4*)(w3l + k0 + 4);
      const f32x4 w1A = *(const f32x4*)(w1l + k0);
      const f32x4 w1B = *(const f32x4*)(w1l + k0 + 4);
      scp += cA.x*w1A.x + cA.y*w1A.y + cA.z*w1A.z + cA.w*w1A.w
           + cB.x*w1B.x + cB.y*w1B.y + cB.z*w1B.z + cB.w*w1B.w;
      bf16x8 bv;
      bv[0] = (__bf16)(cA.x*w3A.x); bv[1] = (__bf16)(cA.y*w3A.y);
      bv[2] = (__bf16)(cA.z*w3A.z); bv[3] = (__bf16)(cA.w*w3A.w);
      bv[4] = (__bf16)(cB.x*w3B.x); bv[5] = (__bf16)(cB.y*w3B.y);
      bv[6] = (__bf16)(cB.z*w3B.z); bv[7] = (__bf16)(cB.w*w3B.w);
      const int j = wv*16 + c16;
      bf16x8 av = *(const bf16x8*)(qsrc + ch*16384 + ks*8192 + j*64 + g*16);
      acc = __builtin_amdgcn_mfma_f32_16x16x32_bf16(av, bv, acc, 0, 0, 0);
    }
  }
  scp += __shfl_xor(scp, 16);
  scp += __shfl_xor(scp, 32);
  const float sc = scp;

  float m = -3.0e38f;
  #pragma unroll
  for (int r = 0; r < 4; ++r){
    int j = wv*16 + g*4 + r;
    float v = msk[j] ? (acc[r] + sc + sqf[j]) : NEGV;
    acc[r] = v;
    m = fmaxf(m, v);
  }
  m = fmaxf(m, __shfl_xor(m, 16));
  m = fmaxf(m, __shfl_xor(m, 32));
  float s = 0.f;
  #pragma unroll
  for (int r = 0; r < 4; ++r){
    float e = __expf(acc[r] - m);
    acc[r] = e; s += e;
  }
  s += __shfl_xor(s, 16);
  s += __shfl_xor(s, 32);
  if (g == 0){ mh[wv][iloc] = m; sh[wv][iloc] = s; }
  __syncthreads();

  float mF = mh[0][iloc];
  #pragma unroll
  for (int q = 1; q < 8; ++q) mF = fmaxf(mF, mh[q][iloc]);
  float sF = 0.f;
  #pragma unroll
  for (int q = 0; q < 8; ++q) sF += sh[q][iloc]*__expf(mh[q][iloc] - mF);
  const float scale = __expf(m - mF) / sF;
  {
    uint64_t pk = (uint64_t)packbf2(acc[0]*scale, acc[1]*scale)
                | ((uint64_t)packbf2(acc[2]*scale, acc[3]*scale) << 32);
    *(uint64_t*)(cw + ((iloc*256 + wv*32 + g*8) ^ ((iloc & 7) << 4))) = pk;
  }
  if (wv == 0 && g == 0) exf[iloc] = __expf(mF);
  __syncthreads();

  bf16x8 pb[4];
  #pragma unroll
  for (int ks = 0; ks < 4; ++ks)
    pb[ks] = *(const bf16x8*)(cw + ((iloc*256 + ks*64 + g*16) ^ ((iloc & 7) << 4)));

  f32x4 a2[4] = {};
  #pragma unroll
  for (int nf = 0; nf < 4; ++nf){
    int hr = nf*16 + c16;
    #pragma unroll
    for (int ks = 0; ks < 4; ++ks){
      bf16x8 qa = *(const bf16x8*)(qtsrc + wv*16384 + ks*4096 + hr*64 + g*16);
      a2[nf] = __builtin_amdgcn_mfma_f32_16x16x32_bf16(qa, pb[ks], a2[nf], 0, 0, 0);
    }
  }
  #pragma unroll
  for (int nf = 0; nf < 4; ++nf){
    int h = wv*64 + nf*16 + g*4;
    const int lo = iloc*2048 + h*4;
    const f32x4 c4 = *(const f32x4*)(lds_c + (lo ^ swz));
    f32x4 av = a2[nf];
    *(f32x4*)(out + rowb*2048 + h)        = c4;
    *(f32x4*)(out + rowb*2048 + 512 + h)  = av;
    f32x4 ca = av * c4;
    *(f32x4*)(out + rowb*2048 + 1024 + h) = ca;
  }

  float n0 = 0.f;
  #pragma unroll
  for (int i2 = 0; i2 < 16; ++i2){
    const int ms = ((i2 & 7) << 4) | (((i2 >> 3) & 1) << 7);
    n0 += exf[i2] * *(const float*)(lds_c + ((i2*2048 + t*4) ^ ms));
  }
  num_part[((size_t)(b*64 + itile))*512 + t] = n0;
  if (t < 16){
    float d = exf[t];
    d += __shfl_down(d, 8, 16); d += __shfl_down(d, 4, 16);
    d += __shfl_down(d, 2, 16); d += __shfl_down(d, 1, 16);
    if (t == 0) den_part[b*64 + itile] = d;
  }
}

// ---------------- K2: reduce partials -> B_vec ------------------------------
__global__ __launch_bounds__(256) void k2_bvec(const float* __restrict__ num_part,
                                               const float* __restrict__ den_part,
                                               float* __restrict__ bvec)
{
  int b = blockIdx.x, t = threadIdx.x;
  float d = 0.f;
  for (int k = 0; k < 64; ++k) d += den_part[b*64 + k];
  float inv = 1.0f / d;
  for (int h = t; h < 512; h += 256){
    float s = 0.f;
    for (int k = 0; k < 64; ++k) s += num_part[(size_t)(b*64 + k)*512 + h];
    bvec[b*512 + h] = s * inv;
  }
}

// ---------------- K3: write C*B_vec chunk -----------------------------------
__global__ __launch_bounds__(256) void k3_cout(const float* __restrict__ C,
                                               const float* __restrict__ bvec,
                                               float* __restrict__ out)
{
  int t = threadIdx.x;
  size_t row = (size_t)blockIdx.x*2 + (t >> 7);
  int col4 = t & 127;
  int b = (int)(row >> 10);
  const f32x4 c4 = *(const f32x4*)(C + row*512 + col4*4);
  const f32x4 bv = *(const f32x4*)(bvec + (size_t)b*512 + col4*4);
  f32x4 cb;
  cb.x = c4.x*bv.x; cb.y = c4.y*bv.y; cb.z = c4.z*bv.z; cb.w = c4.w*bv.w;
  *(f32x4*)(out + row*2048 + 1536 + col4*4) = cb;
}

extern "C" void kernel_launch(void* const* d_in, const int* in_sizes, int n_in,
                              void* d_out, int out_size, void* d_ws, size_t ws_size,
                              hipStream_t stream)
{
  const float* C     = (const float*)d_in[0];
  const float* Q     = (const float*)d_in[1];
  const int*   qmask = (const int*)d_in[2];
  const float* w     = (const float*)d_in[3];
  float* out = (float*)d_out;
  char*  ws  = (char*)d_ws;

  char*  qbf      = ws;                                    // 4 MB
  char*  qtbf     = ws + (4 << 20);                        // 4 MB
  float* sq_part  = (float*)(ws + (8 << 20));              // 64 KB
  float* num_part = (float*)(ws + (8 << 20) + (1 << 16));  // 4 MB (dump first)
  float* den_part = (float*)(ws + (12 << 20) + (1 << 16)); // 8 KB
  float* bvec     = (float*)(ws + (12 << 20) + (1 << 16) + 8192); // 64 KB
  float* dump     = num_part;   // k1_main fully overwrites afterwards

  k0_prep<<<128, 256, 0, stream>>>(Q, w, qbf, qtbf, sq_part);
  // measurement: slowest dispatch by design -> owns the top-5 rows
  k1v_nostores<<<2048, 512, 0, stream>>>(C, qmask, w, sq_part, qbf, qtbf, dump);
  // real pipeline (R10-best, unchanged)
  k1_main<<<2048, 512, 0, stream>>>(C, qmask, w, sq_part, qbf, qtbf,
                                    out, num_part, den_part);
  k2_bvec<<<32, 256, 0, stream>>>(num_part, den_part, bvec);
  k3_cout<<<16384, 256, 0, stream>>>(C, bvec, out);
}

// Round 16
// 116.715 us; speedup vs baseline: 12.0912x; 12.0912x over previous
//
#include <hip/hip_runtime.h>
#include <stdint.h>

#define NEGV (-1000000000.0f)

typedef float  f32x4  __attribute__((ext_vector_type(4)));
typedef __bf16 bf16x8 __attribute__((ext_vector_type(8)));

__device__ __forceinline__ unsigned short f2bf(float f){
  union { float f; unsigned u; } v; v.f = f;
  unsigned r = v.u + 0x7FFFu + ((v.u >> 16) & 1u);
  return (unsigned short)(r >> 16);
}
__device__ __forceinline__ unsigned packbf2(float a, float b){
  return (unsigned)f2bf(a) | ((unsigned)f2bf(b) << 16);
}
__device__ __forceinline__ void gl_lds16(const void* g, const char* l){
  __builtin_amdgcn_global_load_lds(
      (const __attribute__((address_space(1))) void*)g,
      (__attribute__((address_space(3))) void*)(unsigned)(uintptr_t)l,
      16, 0, 0);
}
__device__ __forceinline__ void nt_store4(float* p, f32x4 v){
  __builtin_nontemporal_store(v, (f32x4*)p);
}

// ws layouts (per batch, 128 KB each) — FRAGMENT-CONTIGUOUS:
//  qbf : frag[ch][ks][j][64B]   ch=k/64, ks=(k/32)&1, j=0..127
//  qtbf: frag[hch][ks][hr][64B] hch=h/64, ks=j/32,    hr=h&63

// ---------------- K0: Q -> packed bf16 fragments, s_q partials -------------
__global__ __launch_bounds__(256) void k0_prep(const float* __restrict__ Q,
                                               const float* __restrict__ w,
                                               char* __restrict__ qbf,
                                               char* __restrict__ qtbf,
                                               float* __restrict__ sq_part)
{
  __shared__ float tile[128][129];
  __shared__ float sqs[128];
  const int bid = blockIdx.x, t = threadIdx.x;
  const int b = bid >> 2, hc = bid & 3;
  if (t < 128) sqs[t] = 0.f;
  __syncthreads();
  for (int it = 0; it < 16; ++it){
    int idx = it*256 + t;
    int j = idx >> 5, h4 = idx & 31;
    const f32x4 q4 = *(const f32x4*)(Q + ((size_t)b*128 + j)*512 + hc*128 + h4*4);
    *(f32x4*)(&tile[j][h4*4]) = q4;
    unsigned lo = packbf2(q4.x, q4.y), hi = packbf2(q4.z, q4.w);
    int k = hc*128 + h4*4;
    int o = (k >> 6)*16384 + (((k >> 5) & 1))*8192 + j*64 + (k & 31)*2;
    char* dst = qbf + (size_t)b*131072 + o;
    *(unsigned*)dst = lo; *(unsigned*)(dst + 4) = hi;
    const float* w2 = w + 512 + k;
    float p = q4.x*w2[0] + q4.y*w2[1] + q4.z*w2[2] + q4.w*w2[3];
    for (int s = 16; s > 0; s >>= 1) p += __shfl_down(p, s, 32);
    if ((t & 31) == 0) sqs[j] += p;
  }
  __syncthreads();
  for (int it = 0; it < 32; ++it){
    int idx = it*256 + t;
    int hr = idx >> 6, j2 = idx & 63;
    float a = tile[j2*2][hr], c = tile[j2*2+1][hr];
    int h = hc*128 + hr;
    int o = (h >> 6)*16384 + (j2 >> 4)*4096 + (h & 63)*64 + (j2 & 15)*4;
    *(unsigned*)(qtbf + (size_t)b*131072 + o) = packbf2(a, c);
  }
  if (t < 128) sq_part[(size_t)(b*4 + hc)*128 + t] = sqs[t];
}

// -------- K1: R10-best + NON-TEMPORAL output stores ------------------------
__global__ __launch_bounds__(512, 6) void k1_main(
    const float* __restrict__ C, const int* __restrict__ qmask,
    const float* __restrict__ w, const float* __restrict__ sq_part,
    const char* __restrict__ qbf, const char* __restrict__ qtbf,
    float* __restrict__ out, float* __restrict__ num_part,
    float* __restrict__ den_part)
{
  __shared__ __align__(16) char lds_c[32768];  // C tile 16 x 2KB, src-swizzled
  __shared__ __align__(16) char cw[4096];      // P: 16 rows x 256 B (swizzled)
  __shared__ float w1l[512], w3l[512];
  __shared__ float sqf[128];
  __shared__ int   msk[128];
  __shared__ float exf[16];
  __shared__ float mh[8][16], sh[8][16];

  const int t = threadIdx.x;
  const int bid = blockIdx.x;
  const int xcd = bid & 7, jj = bid >> 3;            // 2048 = 8 x 256
  const int b = xcd*4 + (jj >> 6), itile = jj & 63;  // batch-per-XCD locality
  const int i0 = itile * 16;
  const int wv = t >> 6, ln = t & 63;
  const int g = ln >> 4, c16 = ln & 15;
  const int iloc = c16;              // 0..15

  // ---- burst-stage the 32 KB C tile (deep vmcnt queue, zero VGPR) ----
  {
    const char* ctile = (const char*)(C + (size_t)(b*1024 + i0)*512);
    #pragma unroll
    for (int r = 0; r < 4; ++r){
      const int ob  = wv*4096 + r*1024;
      const int row = ob >> 11;
      const int msw = ((row & 7) << 4) | (((row >> 3) & 1) << 7);
      gl_lds16(ctile + ob + ((ln << 4) ^ msw), lds_c + ob);
    }
  }
  if (t < 128){
    sqf[t] = sq_part[(size_t)(b*4 + 0)*128 + t] + sq_part[(size_t)(b*4 + 1)*128 + t]
           + sq_part[(size_t)(b*4 + 2)*128 + t] + sq_part[(size_t)(b*4 + 3)*128 + t];
    msk[t] = qmask[b*128 + t];
  }
  w1l[t] = w[t];
  w3l[t] = w[1024 + t];
  __syncthreads();   // drains gload_lds + LDS writes

  const char* qsrc  = qbf  + (size_t)b * 131072;
  const char* qtsrc = qtbf + (size_t)b * 131072;
  const size_t rowb = (size_t)(b*1024 + i0 + iloc);
  const int swz = ((iloc & 7) << 4) | (((iloc >> 3) & 1) << 7);

  // ---- S-phase: wave wv computes D[j][i] for j in [wv*16, wv*16+16) ----
  float scp = 0.f;
  f32x4 acc = {};
  #pragma unroll
  for (int ch = 0; ch < 8; ++ch){
    #pragma unroll
    for (int ks = 0; ks < 2; ++ks){
      const int k0 = ch*64 + ks*32 + g*8;
      const int lo = iloc*2048 + k0*4;
      const f32x4 cA  = *(const f32x4*)(lds_c + (lo ^ swz));
      const f32x4 cB  = *(const f32x4*)(lds_c + ((lo + 16) ^ swz));
      const f32x4 w3A = *(const f32x4*)(w3l + k0);
      const f32x4 w3B = *(const f32x4*)(w3l + k0 + 4);
      const f32x4 w1A = *(const f32x4*)(w1l + k0);
      const f32x4 w1B = *(const f32x4*)(w1l + k0 + 4);
      scp += cA.x*w1A.x + cA.y*w1A.y + cA.z*w1A.z + cA.w*w1A.w
           + cB.x*w1B.x + cB.y*w1B.y + cB.z*w1B.z + cB.w*w1B.w;
      bf16x8 bv;
      bv[0] = (__bf16)(cA.x*w3A.x); bv[1] = (__bf16)(cA.y*w3A.y);
      bv[2] = (__bf16)(cA.z*w3A.z); bv[3] = (__bf16)(cA.w*w3A.w);
      bv[4] = (__bf16)(cB.x*w3B.x); bv[5] = (__bf16)(cB.y*w3B.y);
      bv[6] = (__bf16)(cB.z*w3B.z); bv[7] = (__bf16)(cB.w*w3B.w);
      const int j = wv*16 + c16;
      bf16x8 av = *(const bf16x8*)(qsrc + ch*16384 + ks*8192 + j*64 + g*16);
      acc = __builtin_amdgcn_mfma_f32_16x16x32_bf16(av, bv, acc, 0, 0, 0);
    }
  }
  scp += __shfl_xor(scp, 16);
  scp += __shfl_xor(scp, 32);
  const float sc = scp;

  // ---- wave-local softmax eighth ----
  float m = -3.0e38f;
  #pragma unroll
  for (int r = 0; r < 4; ++r){
    int j = wv*16 + g*4 + r;
    float v = msk[j] ? (acc[r] + sc + sqf[j]) : NEGV;
    acc[r] = v;
    m = fmaxf(m, v);
  }
  m = fmaxf(m, __shfl_xor(m, 16));
  m = fmaxf(m, __shfl_xor(m, 32));
  float s = 0.f;
  #pragma unroll
  for (int r = 0; r < 4; ++r){
    float e = __expf(acc[r] - m);
    acc[r] = e; s += e;
  }
  s += __shfl_xor(s, 16);
  s += __shfl_xor(s, 32);
  if (g == 0){ mh[wv][iloc] = m; sh[wv][iloc] = s; }
  __syncthreads();

  // ---- 8-way combine ----
  float mF = mh[0][iloc];
  #pragma unroll
  for (int q = 1; q < 8; ++q) mF = fmaxf(mF, mh[q][iloc]);
  float sF = 0.f;
  #pragma unroll
  for (int q = 0; q < 8; ++q) sF += sh[q][iloc]*__expf(mh[q][iloc] - mF);
  const float scale = __expf(m - mF) / sF;
  {
    uint64_t pk = (uint64_t)packbf2(acc[0]*scale, acc[1]*scale)
                | ((uint64_t)packbf2(acc[2]*scale, acc[3]*scale) << 32);
    *(uint64_t*)(cw + ((iloc*256 + wv*32 + g*8) ^ ((iloc & 7) << 4))) = pk;
  }
  if (wv == 0 && g == 0) exf[iloc] = __expf(mF);
  __syncthreads();

  // ---- PV + fused epilogue (non-temporal stores) ----
  bf16x8 pb[4];
  #pragma unroll
  for (int ks = 0; ks < 4; ++ks)
    pb[ks] = *(const bf16x8*)(cw + ((iloc*256 + ks*64 + g*16) ^ ((iloc & 7) << 4)));

  f32x4 a2[4] = {};
  #pragma unroll
  for (int nf = 0; nf < 4; ++nf){
    int hr = nf*16 + c16;
    #pragma unroll
    for (int ks = 0; ks < 4; ++ks){
      bf16x8 qa = *(const bf16x8*)(qtsrc + wv*16384 + ks*4096 + hr*64 + g*16);
      a2[nf] = __builtin_amdgcn_mfma_f32_16x16x32_bf16(qa, pb[ks], a2[nf], 0, 0, 0);
    }
  }
  #pragma unroll
  for (int nf = 0; nf < 4; ++nf){
    int h = wv*64 + nf*16 + g*4;
    const int lo = iloc*2048 + h*4;
    const f32x4 c4 = *(const f32x4*)(lds_c + (lo ^ swz));
    f32x4 av = a2[nf];
    nt_store4(out + rowb*2048 + h,        c4);          // C copy
    nt_store4(out + rowb*2048 + 512 + h,  av);          // A
    f32x4 ca = av * c4;
    nt_store4(out + rowb*2048 + 1024 + h, ca);          // C*A
  }

  // ---- B_vec partials ----
  float n0 = 0.f;
  #pragma unroll
  for (int i2 = 0; i2 < 16; ++i2){
    const int ms = ((i2 & 7) << 4) | (((i2 >> 3) & 1) << 7);
    n0 += exf[i2] * *(const float*)(lds_c + ((i2*2048 + t*4) ^ ms));
  }
  num_part[((size_t)(b*64 + itile))*512 + t] = n0;
  if (t < 16){
    float d = exf[t];
    d += __shfl_down(d, 8, 16); d += __shfl_down(d, 4, 16);
    d += __shfl_down(d, 2, 16); d += __shfl_down(d, 1, 16);
    if (t == 0) den_part[b*64 + itile] = d;
  }
}

// ---------------- K2: reduce partials -> B_vec ------------------------------
__global__ __launch_bounds__(256) void k2_bvec(const float* __restrict__ num_part,
                                               const float* __restrict__ den_part,
                                               float* __restrict__ bvec)
{
  int b = blockIdx.x, t = threadIdx.x;
  float d = 0.f;
  for (int k = 0; k < 64; ++k) d += den_part[b*64 + k];
  float inv = 1.0f / d;
  for (int h = t; h < 512; h += 256){
    float s = 0.f;
    for (int k = 0; k < 64; ++k) s += num_part[(size_t)(b*64 + k)*512 + h];
    bvec[b*512 + h] = s * inv;
  }
}

// ---------------- K3: write C*B_vec chunk (non-temporal) --------------------
__global__ __launch_bounds__(256) void k3_cout(const float* __restrict__ C,
                                               const float* __restrict__ bvec,
                                               float* __restrict__ out)
{
  int t = threadIdx.x;
  size_t row = (size_t)blockIdx.x*2 + (t >> 7);
  int col4 = t & 127;
  int b = (int)(row >> 10);
  const f32x4 c4 = *(const f32x4*)(C + row*512 + col4*4);
  const f32x4 bv = *(const f32x4*)(bvec + (size_t)b*512 + col4*4);
  f32x4 cb;
  cb.x = c4.x*bv.x; cb.y = c4.y*bv.y; cb.z = c4.z*bv.z; cb.w = c4.w*bv.w;
  __builtin_nontemporal_store(cb, (f32x4*)(out + row*2048 + 1536 + col4*4));
}

extern "C" void kernel_launch(void* const* d_in, const int* in_sizes, int n_in,
                              void* d_out, int out_size, void* d_ws, size_t ws_size,
                              hipStream_t stream)
{
  const float* C     = (const float*)d_in[0];
  const float* Q     = (const float*)d_in[1];
  const int*   qmask = (const int*)d_in[2];
  const float* w     = (const float*)d_in[3];
  float* out = (float*)d_out;
  char*  ws  = (char*)d_ws;

  char*  qbf      = ws;                                    // 4 MB
  char*  qtbf     = ws + (4 << 20);                        // 4 MB
  float* sq_part  = (float*)(ws + (8 << 20));              // 64 KB
  float* num_part = (float*)(ws + (8 << 20) + (1 << 16));  // 4 MB
  float* den_part = (float*)(ws + (12 << 20) + (1 << 16)); // 8 KB
  float* bvec     = (float*)(ws + (12 << 20) + (1 << 16) + 8192); // 64 KB

  k0_prep<<<128, 256, 0, stream>>>(Q, w, qbf, qtbf, sq_part);
  k1_main<<<2048, 512, 0, stream>>>(C, qmask, w, sq_part, qbf, qtbf,
                                    out, num_part, den_part);
  k2_bvec<<<32, 256, 0, stream>>>(num_part, den_part, bvec);
  k3_cout<<<16384, 256, 0, stream>>>(C, bvec, out);
}